// Round 15
// baseline (440.525 us; speedup 1.0000x reference)
//
#include <hip/hip_runtime.h>
#include <hip/hip_bf16.h>

typedef __attribute__((ext_vector_type(8))) short bf16x8;
typedef __attribute__((ext_vector_type(4))) float f32x4;

__device__ __forceinline__ ushort f2bf(float f) {
  union { float f; unsigned u; } v; v.f = f;
  unsigned u = v.u;
  return (ushort)((u + 0x7FFFu + ((u >> 16) & 1u)) >> 16);
}
__device__ __forceinline__ float bf2f(ushort u) {
  union { unsigned u; float f; } v; v.u = ((unsigned)u) << 16;
  return v.f;
}
__device__ __forceinline__ float fsig(float x) {
  return __builtin_amdgcn_rcpf(1.0f + __expf(-x));
}
__device__ __forceinline__ float ftnh(float x) {
  float e = __expf(2.0f * x);
  return 1.0f - 2.0f * __builtin_amdgcn_rcpf(e + 1.0f);
}
__device__ __forceinline__ f32x4 MF(bf16x8 a, bf16x8 b, f32x4 c) {
  return __builtin_amdgcn_mfma_f32_16x16x32_bf16(a, b, c, 0, 0, 0);
}

// Repack layout (ushort units) in `wall`:
//  [0,131072)        whhrep [dir2][w8][lane64][frag16][8]
//  [131072,262144)   wihrep [dir2][wq4][j8][kk4][lane64][8]
//  [262144,294912)   linrep [w8][kk8][lane64][8]
//  [294912,425984)   emb_bf [1024][128]
__global__ __launch_bounds__(256) void repack_all2(
    const float* __restrict__ wihf, const float* __restrict__ whhf,
    const float* __restrict__ wihb, const float* __restrict__ whhb,
    const float* __restrict__ emb, const float* __restrict__ linw,
    ushort* __restrict__ wall) {
  int i = blockIdx.x * 256 + threadIdx.x;
  if (i < 131072) {
    int e = i & 7, f = (i >> 3) & 15, lane = (i >> 7) & 63, w = (i >> 13) & 7,
        d = (i >> 16) & 1;
    int nt = f >> 2, kk = f & 3;
    int pcol = w * 64 + nt * 16 + (lane & 15);
    int g = (pcol >> 4) & 3, h = (pcol >> 6) * 16 + (pcol & 15);
    int k = kk * 32 + (lane >> 4) * 8 + e;
    const float* src = d ? whhb : whhf;
    wall[i] = f2bf(src[(g * 128 + h) * 128 + k]);
  } else if (i < 262144) {
    int r = i - 131072;
    int e = r & 7, lane = (r >> 3) & 63, kk = (r >> 9) & 3, j = (r >> 11) & 7,
        wq = (r >> 14) & 3, d = (r >> 16) & 1;
    int pcol = wq * 128 + j * 16 + (lane & 15);
    int g = (pcol >> 4) & 3, h = (pcol >> 6) * 16 + (pcol & 15);
    int k = kk * 32 + (lane >> 4) * 8 + e;
    const float* src = d ? wihb : wihf;
    wall[i] = f2bf(src[(g * 128 + h) * 128 + k]);
  } else if (i < 294912) {
    int r = i - 262144;
    int e = r & 7, lane = (r >> 3) & 63, kk = (r >> 9) & 7, w = (r >> 12) & 7;
    int col = w * 16 + (lane & 15);
    int k = kk * 32 + (lane >> 4) * 8 + e;
    wall[i] = f2bf(linw[col * 256 + k]);
  } else if (i < 425984) {
    int r = i - 294912;
    wall[i] = f2bf(emb[r]);
  }
}

// Fused vocab pipeline: x-gates (-> gxv), leaf scan (T=2), leaf head+gates
// (-> gcv). One block per 16 vocab entries. (Proven rounds 9-14.)
__global__ __launch_bounds__(512) void vocab_all(
    const ushort* __restrict__ emb_bf, const ushort* __restrict__ wihrep,
    const ushort* __restrict__ whhrep, const ushort* __restrict__ linrep,
    const float* __restrict__ linb, const float* __restrict__ bihf,
    const float* __restrict__ bhhf, const float* __restrict__ bihb,
    const float* __restrict__ bhhb, ushort* __restrict__ gxv,
    ushort* __restrict__ gcv) {
  __shared__ __align__(16) ushort sT[2048];
  __shared__ __align__(16) ushort sGx[16384];
  __shared__ __align__(16) ushort sHf[2][2048];
  __shared__ __align__(16) ushort sH[2048];
  const int tid = threadIdx.x;
  const int w = tid >> 6, l = tid & 63, hlo = l & 15, lg = l >> 4;
  const int r0 = lg * 4, k0 = lg * 8;
  const int hcol = w * 16 + hlo;
  const int v0 = blockIdx.x * 16;

  {
    int row = tid >> 5, col0 = (tid & 31) * 4;
    *(ushort4*)(sT + row * 128 + (col0 ^ ((row & 7) << 3))) =
        *(const ushort4*)(emb_bf + (size_t)(v0 + row) * 128 + col0);
  }
  __syncthreads();
  const int dd = w >> 2, wq = w & 3;
  {
    const ushort* wp = wihrep + (size_t)(dd * 4 + wq) * 16384 + l * 8;
    bf16x8 wfv[32];
#pragma unroll
    for (int j = 0; j < 8; ++j)
#pragma unroll
      for (int kk = 0; kk < 4; ++kk)
        wfv[j * 4 + kk] = *(const bf16x8*)(wp + j * 2048 + kk * 512);
    bf16x8 a[4];
#pragma unroll
    for (int kk = 0; kk < 4; ++kk)
      a[kk] = *(const bf16x8*)(sT + hlo * 128 + ((kk * 32 + k0) ^ ((hlo & 7) << 3)));
    f32x4 acc[8];
#pragma unroll
    for (int j = 0; j < 8; ++j) { f32x4 z = {0.f, 0.f, 0.f, 0.f}; acc[j] = z; }
#pragma unroll
    for (int kk = 0; kk < 4; ++kk)
#pragma unroll
      for (int j = 0; j < 8; ++j) acc[j] = MF(a[kk], wfv[j * 4 + kk], acc[j]);
#pragma unroll
    for (int p = 0; p < 2; ++p)
#pragma unroll
      for (int rg = 0; rg < 4; ++rg) {
        int hid = (wq * 2 + p) * 16 + hlo;
        ushort4 q = {f2bf(acc[p * 4 + 0][rg]), f2bf(acc[p * 4 + 1][rg]),
                     f2bf(acc[p * 4 + 2][rg]), f2bf(acc[p * 4 + 3][rg])};
        *(ushort4*)(gxv + (size_t)(v0 + r0 + rg) * 1024 + dd * 512 + hid * 4) = q;
        *(ushort4*)(sGx + (r0 + rg) * 1024 + dd * 512 + hid * 4) = q;
      }
  }
  __syncthreads();

  for (int d = 0; d < 2; ++d) {
    bf16x8 whh[16];
    {
      const ushort* p = whhrep + d * 65536 + w * 8192 + l * 128;
#pragma unroll
      for (int f = 0; f < 16; ++f) whh[f] = *(const bf16x8*)(p + f * 8);
    }
    const float* bih = d ? bihb : bihf;
    const float* bhh = d ? bhhb : bhhf;
    float bs[4];
#pragma unroll
    for (int nt = 0; nt < 4; ++nt)
      bs[nt] = bih[nt * 128 + hcol] + bhh[nt * 128 + hcol];
    ushort4 xg[4];
#pragma unroll
    for (int rg = 0; rg < 4; ++rg)
      xg[rg] = *(const ushort4*)(sGx + (r0 + rg) * 1024 + d * 512 + hcol * 4);
    float c_st[4], hn[4];
#pragma unroll
    for (int rg = 0; rg < 4; ++rg) {
      float g0 = bf2f(xg[rg].x) + bs[0];
      float g2 = bf2f(xg[rg].z) + bs[2];
      float g3 = bf2f(xg[rg].w) + bs[3];
      float c = fsig(g0) * ftnh(g2);
      c_st[rg] = c;
      hn[rg] = fsig(g3) * ftnh(c);
    }
#pragma unroll
    for (int rg = 0; rg < 4; ++rg) {
      int rr = r0 + rg;
      sH[rr * 128 + (hcol ^ ((rr & 7) << 3))] = f2bf(hn[rg]);
    }
    __syncthreads();
    f32x4 a4[4];
#pragma unroll
    for (int rg = 0; rg < 4; ++rg)
#pragma unroll
      for (int nt = 0; nt < 4; ++nt)
        a4[nt][rg] = bf2f(((const ushort*)&xg[rg])[nt]) + bs[nt];
    bf16x8 ah[4];
#pragma unroll
    for (int kk = 0; kk < 4; ++kk)
      ah[kk] = *(const bf16x8*)(sH + hlo * 128 + ((kk * 32 + k0) ^ ((hlo & 7) << 3)));
#pragma unroll
    for (int kk = 0; kk < 4; ++kk)
#pragma unroll
      for (int nt = 0; nt < 4; ++nt) a4[nt] = MF(ah[kk], whh[nt * 4 + kk], a4[nt]);
#pragma unroll
    for (int rg = 0; rg < 4; ++rg) {
      float iv = fsig(a4[0][rg]);
      float fv = fsig(a4[1][rg]);
      float gv = ftnh(a4[2][rg]);
      float ov = fsig(a4[3][rg]);
      float c = fv * c_st[rg] + iv * gv;
      int rr = r0 + rg;
      sHf[d][rr * 128 + (hcol ^ ((rr & 7) << 3))] = f2bf(ov * ftnh(c));
    }
    __syncthreads();
  }

  {
    const float lb = linb[hcol];
    f32x4 hac = {lb, lb, lb, lb};
#pragma unroll
    for (int kk = 0; kk < 8; ++kk) {
      bf16x8 lfr = *(const bf16x8*)(linrep + w * 4096 + kk * 512 + l * 8);
      bf16x8 af = *(const bf16x8*)(&sHf[kk >> 2][0] + hlo * 128 +
                                   (((kk & 3) * 32 + k0) ^ ((hlo & 7) << 3)));
      hac = MF(af, lfr, hac);
    }
#pragma unroll
    for (int rg = 0; rg < 4; ++rg) {
      int rr = r0 + rg;
      sT[rr * 128 + (hcol ^ ((rr & 7) << 3))] = f2bf(ftnh(hac[rg]));
    }
    __syncthreads();
    const ushort* wp = wihrep + (size_t)(dd * 4 + wq) * 16384 + l * 8;
    bf16x8 a[4];
#pragma unroll
    for (int kk = 0; kk < 4; ++kk)
      a[kk] = *(const bf16x8*)(sT + hlo * 128 + ((kk * 32 + k0) ^ ((hlo & 7) << 3)));
    f32x4 acc[8];
#pragma unroll
    for (int j = 0; j < 8; ++j) { f32x4 z = {0.f, 0.f, 0.f, 0.f}; acc[j] = z; }
#pragma unroll
    for (int kk = 0; kk < 4; ++kk)
#pragma unroll
      for (int j = 0; j < 8; ++j) {
        bf16x8 wf = *(const bf16x8*)(wp + j * 2048 + kk * 512);
        acc[j] = MF(a[kk], wf, acc[j]);
      }
#pragma unroll
    for (int p = 0; p < 2; ++p)
#pragma unroll
      for (int rg = 0; rg < 4; ++rg) {
        int hid = (wq * 2 + p) * 16 + hlo;
        ushort4 q = {f2bf(acc[p * 4 + 0][rg]), f2bf(acc[p * 4 + 1][rg]),
                     f2bf(acc[p * 4 + 2][rg]), f2bf(acc[p * 4 + 3][rg])};
        *(ushort4*)(gcv + (size_t)(v0 + r0 + rg) * 1024 + dd * 512 + hid * 4) = q;
      }
  }
}

// Level scan, PARALLEL DIRECTIONS: 16 waves, waves 0-7 = dir0, 8-15 = dir1.
// 6 barrier-steps total (was 12). Per-wave code identical to the proven
// R13 scan. Ends with head + own-gates -> gdst (16 waves = 16 gate units).
template <int MT, bool CLAB>
__global__ __launch_bounds__(1024) void scan_lvl5(
    const int* __restrict__ xlab, const int* __restrict__ clab,
    const ushort* __restrict__ gxv, const ushort* __restrict__ gsrc,
    const ushort* __restrict__ wihrep, const ushort* __restrict__ whhrep,
    const ushort* __restrict__ linrep, const float* __restrict__ linb,
    const float* __restrict__ bihf, const float* __restrict__ bhhf,
    const float* __restrict__ bihb, const float* __restrict__ bhhb,
    ushort* __restrict__ gdst) {
  __shared__ __align__(16) ushort sH[2][2][MT * 2048];   // [dir][buf]
  __shared__ __align__(16) ushort sHF[2][MT * 2048];     // [dir]
  __shared__ __align__(16) ushort sT[2048];
  __shared__ int sLabX[MT * 16];
  __shared__ int sLabC[CLAB ? MT * 64 : 1];

  const int tid = threadIdx.x;
  const int w16 = tid >> 6;
  const int d = w16 >> 3;       // wave's direction
  const int w = w16 & 7;        // hidden-slice wave within dir
  const int l = tid & 63, hlo = l & 15, lg = l >> 4;
  const int r0 = lg * 4, k0 = lg * 8;
  const int hcol = w * 16 + hlo;
  const int axswz = (hlo & 7) << 3;
  const int n0 = blockIdx.x * (MT * 16);

  for (int i = tid; i < MT * 16; i += 1024) sLabX[i] = xlab[n0 + i];
  if (CLAB)
    for (int i = tid; i < MT * 64; i += 1024) sLabC[i] = clab[4 * n0 + i];
  __syncthreads();

  bf16x8 whh[16];
  {
    const ushort* p = whhrep + d * 65536 + w * 8192 + l * 128;
#pragma unroll
    for (int f = 0; f < 16; ++f) whh[f] = *(const bf16x8*)(p + f * 8);
  }
  const float* bih = d ? bihb : bihf;
  const float* bhh = d ? bhhb : bhhf;
  float bs[4];
#pragma unroll
  for (int nt = 0; nt < 4; ++nt)
    bs[nt] = bih[nt * 128 + hcol] + bhh[nt * 128 + hcol];

  float c_st[MT][4];
  // t = 0 : x-gates only (h0 = 0)
#pragma unroll
  for (int mt = 0; mt < MT; ++mt) {
    ushort4 xg[4];
#pragma unroll
    for (int rg = 0; rg < 4; ++rg) {
      int ln = mt * 16 + r0 + rg;
      xg[rg] = *(const ushort4*)(gxv + (size_t)sLabX[ln] * 1024 + d * 512 +
                                 hcol * 4);
    }
#pragma unroll
    for (int rg = 0; rg < 4; ++rg) {
      float g0 = bf2f(xg[rg].x) + bs[0];
      float g2 = bf2f(xg[rg].z) + bs[2];
      float g3 = bf2f(xg[rg].w) + bs[3];
      float c = fsig(g0) * ftnh(g2);
      c_st[mt][rg] = c;
      float h = fsig(g3) * ftnh(c);
      int rr = r0 + rg;
      sH[d][0][mt * 2048 + rr * 128 + (hcol ^ ((rr & 7) << 3))] = f2bf(h);
    }
  }
  __syncthreads();

#pragma unroll
  for (int t = 1; t < 6; ++t) {
    // issue this step's gate loads upfront (consumed post-MFMA)
    ushort4 gv[MT][4];
    if (t < 5) {
      const int ci = d ? (4 - t) : (t - 1);
#pragma unroll
      for (int mt = 0; mt < MT; ++mt)
#pragma unroll
        for (int rg = 0; rg < 4; ++rg) {
          int ln = mt * 16 + r0 + rg;
          size_t row =
              CLAB ? (size_t)sLabC[ln * 4 + ci] : (size_t)(4 * (n0 + ln) + ci);
          gv[mt][rg] = *(const ushort4*)(gsrc + row * 1024 + d * 512 + hcol * 4);
        }
    } else {
#pragma unroll
      for (int mt = 0; mt < MT; ++mt)
#pragma unroll
        for (int rg = 0; rg < 4; ++rg) {
          int ln = mt * 16 + r0 + rg;
          gv[mt][rg] = *(const ushort4*)(gxv + (size_t)sLabX[ln] * 1024 +
                                         d * 512 + hcol * 4);
        }
    }
#pragma unroll
    for (int mt = 0; mt < MT; ++mt) {
      f32x4 a4[4];
#pragma unroll
      for (int nt = 0; nt < 4; ++nt) {
        f32x4 z = {bs[nt], bs[nt], bs[nt], bs[nt]};
        a4[nt] = z;
      }
      bf16x8 ah[4];
#pragma unroll
      for (int kk = 0; kk < 4; ++kk)
        ah[kk] = *(const bf16x8*)(&sH[d][(t + 1) & 1][mt * 2048] + hlo * 128 +
                                  ((kk * 32 + k0) ^ axswz));
#pragma unroll
      for (int kk = 0; kk < 4; ++kk)
#pragma unroll
        for (int nt = 0; nt < 4; ++nt)
          a4[nt] = MF(ah[kk], whh[nt * 4 + kk], a4[nt]);
#pragma unroll
      for (int rg = 0; rg < 4; ++rg) {
        a4[0][rg] += bf2f(gv[mt][rg].x);
        a4[1][rg] += bf2f(gv[mt][rg].y);
        a4[2][rg] += bf2f(gv[mt][rg].z);
        a4[3][rg] += bf2f(gv[mt][rg].w);
      }
      float hn[4];
#pragma unroll
      for (int rg = 0; rg < 4; ++rg) {
        float iv = fsig(a4[0][rg]);
        float fv = fsig(a4[1][rg]);
        float gg = ftnh(a4[2][rg]);
        float ov = fsig(a4[3][rg]);
        float c = fv * c_st[mt][rg] + iv * gg;
        c_st[mt][rg] = c;
        hn[rg] = ov * ftnh(c);
      }
      ushort* dstp =
          (t < 5) ? &sH[d][t & 1][mt * 2048] : &sHF[d][mt * 2048];
#pragma unroll
      for (int rg = 0; rg < 4; ++rg) {
        int rr = r0 + rg;
        dstp[rr * 128 + (hcol ^ ((rr & 7) << 3))] = f2bf(hn[rg]);
      }
    }
    __syncthreads();
  }

  // ---- head + own gates: 16 waves = (dir2 x wq4 x half2) gate units ----
  const int wq = (w16 >> 1) & 3;
  const int half = w16 & 1;
  const float lb = linb[hcol];
  bf16x8 lf[8];
#pragma unroll
  for (int kk = 0; kk < 8; ++kk)
    lf[kk] = *(const bf16x8*)(linrep + w * 4096 + kk * 512 + l * 8);
#pragma unroll
  for (int mt = 0; mt < MT; ++mt) {
    f32x4 hac = {lb, lb, lb, lb};
#pragma unroll
    for (int kk = 0; kk < 8; ++kk) {
      bf16x8 af = *(const bf16x8*)(&sHF[kk >> 2][mt * 2048] + hlo * 128 +
                                   (((kk & 3) * 32 + k0) ^ axswz));
      hac = MF(af, lf[kk], hac);
    }
    __syncthreads();  // prev mt's sT reads complete
    if (w16 < 8) {
#pragma unroll
      for (int rg = 0; rg < 4; ++rg) {
        int rr = r0 + rg;
        sT[rr * 128 + (hcol ^ ((rr & 7) << 3))] = f2bf(ftnh(hac[rg]));
      }
    }
    __syncthreads();
    bf16x8 a[4];
#pragma unroll
    for (int kk = 0; kk < 4; ++kk)
      a[kk] = *(const bf16x8*)(sT + hlo * 128 + ((kk * 32 + k0) ^ axswz));
    const ushort* wp = wihrep + (size_t)(d * 4 + wq) * 16384 +
                       (size_t)(half * 4) * 2048 + l * 8;
    f32x4 acc[4];
#pragma unroll
    for (int j = 0; j < 4; ++j) { f32x4 z = {0.f, 0.f, 0.f, 0.f}; acc[j] = z; }
#pragma unroll
    for (int kk = 0; kk < 4; ++kk)
#pragma unroll
      for (int j = 0; j < 4; ++j) {
        bf16x8 wf = *(const bf16x8*)(wp + j * 2048 + kk * 512);
        acc[j] = MF(a[kk], wf, acc[j]);
      }
    const int hid = (wq * 2 + half) * 16 + hlo;
#pragma unroll
    for (int rg = 0; rg < 4; ++rg) {
      int n = n0 + mt * 16 + r0 + rg;
      ushort4 q = {f2bf(acc[0][rg]), f2bf(acc[1][rg]), f2bf(acc[2][rg]),
                   f2bf(acc[3][rg])};
      *(ushort4*)(gdst + (size_t)n * 1024 + d * 512 + hid * 4) = q;
    }
  }
}

// Levels 2,1,0 + final head in ONE 1024-thread block, dirs parallel.
__global__ __launch_bounds__(1024) void tail_lvls5(
    const int* __restrict__ labels, const ushort* __restrict__ gxv,
    const ushort* __restrict__ gc3, const ushort* __restrict__ wihrep,
    const ushort* __restrict__ whhrep, const ushort* __restrict__ linrep,
    const float* __restrict__ linb, const float* __restrict__ bihf,
    const float* __restrict__ bhhf, const float* __restrict__ bihb,
    const float* __restrict__ bhhb, float* __restrict__ outp) {
  __shared__ __align__(16) ushort sH[2][2][2048];
  __shared__ __align__(16) ushort sHF[2][2048];
  __shared__ __align__(16) ushort sT[2048];
  __shared__ __align__(16) ushort sGc[16384];

  const int tid = threadIdx.x;
  const int w16 = tid >> 6;
  const int d = w16 >> 3;
  const int w = w16 & 7;
  const int l = tid & 63, hlo = l & 15, lg = l >> 4;
  const int r0 = lg * 4, k0 = lg * 8;
  const int hcol = w * 16 + hlo;
  const int axswz = (hlo & 7) << 3;
  const int wq = (w16 >> 1) & 3;
  const int half = w16 & 1;

  bf16x8 whh[16];
  {
    const ushort* pw = whhrep + d * 65536 + w * 8192 + l * 128;
#pragma unroll
    for (int f = 0; f < 16; ++f) whh[f] = *(const bf16x8*)(pw + f * 8);
  }
  const float* bih = d ? bihb : bihf;
  const float* bhh = d ? bhhb : bhhf;
  float bs[4];
#pragma unroll
  for (int nt = 0; nt < 4; ++nt)
    bs[nt] = bih[nt * 128 + hcol] + bhh[nt * 128 + hcol];

  bf16x8 lf[8];
#pragma unroll
  for (int kk = 0; kk < 8; ++kk)
    lf[kk] = *(const bf16x8*)(linrep + w * 4096 + kk * 512 + l * 8);
  const float lb = linb[hcol];
  const int cnts[3] = {16, 4, 1};
  const int xoffs[3] = {5, 1, 0};

  for (int p = 0; p < 3; ++p) {
    const int cnt = cnts[p];
    const int* xlab = labels + xoffs[p];
    const ushort* gsrc = (p == 0) ? gc3 : (const ushort*)sGc;
    int nnr[4];
#pragma unroll
    for (int rg = 0; rg < 4; ++rg) {
      int n = r0 + rg;
      nnr[rg] = (n < cnt) ? n : (cnt - 1);
    }

    ushort4 xg[4];
#pragma unroll
    for (int rg = 0; rg < 4; ++rg)
      xg[rg] = *(const ushort4*)(gxv + (size_t)xlab[nnr[rg]] * 1024 + d * 512 +
                                 hcol * 4);
    float c_st[4];
#pragma unroll
    for (int t = 0; t < 6; ++t) {
      const bool isx = (t == 0) || (t == 5);
      f32x4 a4[4];
#pragma unroll
      for (int rg = 0; rg < 4; ++rg) {
        ushort4 u;
        if (isx) {
          u = xg[rg];
        } else {
          const int ci = d ? (4 - t) : (t - 1);
          int row = 4 * nnr[rg] + ci;
          u = *(const ushort4*)(gsrc + (size_t)row * 1024 + d * 512 + hcol * 4);
        }
#pragma unroll
        for (int nt = 0; nt < 4; ++nt)
          a4[nt][rg] = bf2f(((const ushort*)&u)[nt]) + bs[nt];
      }
      if (t > 0) {
        bf16x8 ah[4];
#pragma unroll
        for (int kk = 0; kk < 4; ++kk)
          ah[kk] = *(const bf16x8*)(&sH[d][(t + 1) & 1][0] + hlo * 128 +
                                    ((kk * 32 + k0) ^ axswz));
#pragma unroll
        for (int kk = 0; kk < 4; ++kk)
#pragma unroll
          for (int nt = 0; nt < 4; ++nt)
            a4[nt] = MF(ah[kk], whh[nt * 4 + kk], a4[nt]);
      }
      float hn[4];
#pragma unroll
      for (int rg = 0; rg < 4; ++rg) {
        float iv = fsig(a4[0][rg]);
        float fv = fsig(a4[1][rg]);
        float gv = ftnh(a4[2][rg]);
        float ov = fsig(a4[3][rg]);
        float c = (t == 0) ? (iv * gv) : (fv * c_st[rg] + iv * gv);
        c_st[rg] = c;
        hn[rg] = ov * ftnh(c);
      }
      ushort* dstp = (t < 5) ? &sH[d][t & 1][0] : &sHF[d][0];
#pragma unroll
      for (int rg = 0; rg < 4; ++rg) {
        int rr = r0 + rg;
        dstp[rr * 128 + (hcol ^ ((rr & 7) << 3))] = f2bf(hn[rg]);
      }
      __syncthreads();
    }

    // head of this level's tile
    f32x4 hac = {lb, lb, lb, lb};
#pragma unroll
    for (int kk = 0; kk < 8; ++kk) {
      bf16x8 af = *(const bf16x8*)(&sHF[kk >> 2][0] + hlo * 128 +
                                   (((kk & 3) * 32 + k0) ^ axswz));
      hac = MF(af, lf[kk], hac);
    }
    if (p == 2) {
      if (w16 < 8 && lg == 0) outp[hcol] = ftnh(hac[0]);
      return;
    }
    __syncthreads();
    if (w16 < 8) {
#pragma unroll
      for (int rg = 0; rg < 4; ++rg) {
        int rr = r0 + rg;
        sT[rr * 128 + (hcol ^ ((rr & 7) << 3))] = f2bf(ftnh(hac[rg]));
      }
    }
    __syncthreads();
    bf16x8 a[4];
#pragma unroll
    for (int kk = 0; kk < 4; ++kk)
      a[kk] = *(const bf16x8*)(sT + hlo * 128 + ((kk * 32 + k0) ^ axswz));
    const ushort* wp = wihrep + (size_t)(d * 4 + wq) * 16384 +
                       (size_t)(half * 4) * 2048 + l * 8;
    f32x4 acc[4];
#pragma unroll
    for (int j = 0; j < 4; ++j) { f32x4 z = {0.f, 0.f, 0.f, 0.f}; acc[j] = z; }
#pragma unroll
    for (int kk = 0; kk < 4; ++kk)
#pragma unroll
      for (int j = 0; j < 4; ++j) {
        bf16x8 wf = *(const bf16x8*)(wp + j * 2048 + kk * 512);
        acc[j] = MF(a[kk], wf, acc[j]);
      }
    const int hid = (wq * 2 + half) * 16 + hlo;
#pragma unroll
    for (int rg = 0; rg < 4; ++rg) {
      int n = r0 + rg;
      if (n < cnt) {
        ushort4 q = {f2bf(acc[0][rg]), f2bf(acc[1][rg]), f2bf(acc[2][rg]),
                     f2bf(acc[3][rg])};
        *(ushort4*)(sGc + (size_t)n * 1024 + d * 512 + hid * 4) = q;
      }
    }
    __syncthreads();
  }
}

extern "C" void kernel_launch(void* const* d_in, const int* in_sizes, int n_in,
                              void* d_out, int out_size, void* d_ws, size_t ws_size,
                              hipStream_t stream) {
  const int* labels = (const int*)d_in[0];
  const float* emb = (const float*)d_in[1];
  const float* w_ih_f = (const float*)d_in[2];
  const float* w_hh_f = (const float*)d_in[3];
  const float* b_ih_f = (const float*)d_in[4];
  const float* b_hh_f = (const float*)d_in[5];
  const float* w_ih_b = (const float*)d_in[6];
  const float* w_hh_b = (const float*)d_in[7];
  const float* b_ih_b = (const float*)d_in[8];
  const float* b_hh_b = (const float*)d_in[9];
  const float* lin_w = (const float*)d_in[10];
  const float* lin_b = (const float*)d_in[11];
  float* out = (float*)d_out;

  ushort* gxv = (ushort*)d_ws;         // 1,048,576
  ushort* gcA = gxv + 1048576;         // 16,777,216 (L7 / L5 / L3 gates)
  ushort* gcB = gcA + 16777216;        // 4,194,304  (gcv / L6 / L4 gates)
  ushort* gcv = gcB;
  ushort* wall = gcB + 4194304;        // 425,984
  ushort* whhrep = wall;
  ushort* wihrep = wall + 131072;
  ushort* linrep = wall + 262144;
  ushort* emb_bf = wall + 294912;

  repack_all2<<<1664, 256, 0, stream>>>(w_ih_f, w_hh_f, w_ih_b, w_hh_b, emb,
                                        lin_w, wall);
  vocab_all<<<64, 512, 0, stream>>>(emb_bf, wihrep, whhrep, linrep, lin_b,
                                    b_ih_f, b_hh_f, b_ih_b, b_hh_b, gxv, gcv);
  // L7: 16384 nodes, 64/block (MT=4, dirs parallel) -> 256 blocks, one pass
  scan_lvl5<4, true><<<256, 1024, 0, stream>>>(
      labels + 5461, labels + 21845, gxv, gcv, wihrep, whhrep, linrep, lin_b,
      b_ih_f, b_hh_f, b_ih_b, b_hh_b, gcA);
  // L6: 4096 nodes, 16/block -> 256 blocks
  scan_lvl5<1, false><<<256, 1024, 0, stream>>>(
      labels + 1365, nullptr, gxv, gcA, wihrep, whhrep, linrep, lin_b, b_ih_f,
      b_hh_f, b_ih_b, b_hh_b, gcB);
  // L5: 1024 -> 64 blocks
  scan_lvl5<1, false><<<64, 1024, 0, stream>>>(
      labels + 341, nullptr, gxv, gcB, wihrep, whhrep, linrep, lin_b, b_ih_f,
      b_hh_f, b_ih_b, b_hh_b, gcA);
  // L4: 256 -> 16 blocks
  scan_lvl5<1, false><<<16, 1024, 0, stream>>>(
      labels + 85, nullptr, gxv, gcA, wihrep, whhrep, linrep, lin_b, b_ih_f,
      b_hh_f, b_ih_b, b_hh_b, gcB);
  // L3: 64 -> 4 blocks
  scan_lvl5<1, false><<<4, 1024, 0, stream>>>(
      labels + 21, nullptr, gxv, gcB, wihrep, whhrep, linrep, lin_b, b_ih_f,
      b_hh_f, b_ih_b, b_hh_b, gcA);
  // L2+L1+L0+head, one block
  tail_lvls5<<<1, 1024, 0, stream>>>(labels, gxv, gcA, wihrep, whhrep, linrep,
                                     lin_b, b_ih_f, b_hh_f, b_ih_b, b_hh_b, out);
}

// Round 16
// 266.462 us; speedup vs baseline: 1.6532x; 1.6532x over previous
//
#include <hip/hip_runtime.h>
#include <hip/hip_bf16.h>

typedef __attribute__((ext_vector_type(8))) short bf16x8;
typedef __attribute__((ext_vector_type(4))) float f32x4;

__device__ __forceinline__ ushort f2bf(float f) {
  union { float f; unsigned u; } v; v.f = f;
  unsigned u = v.u;
  return (ushort)((u + 0x7FFFu + ((u >> 16) & 1u)) >> 16);
}
__device__ __forceinline__ float bf2f(ushort u) {
  union { unsigned u; float f; } v; v.u = ((unsigned)u) << 16;
  return v.f;
}
__device__ __forceinline__ float fsig(float x) {
  return __builtin_amdgcn_rcpf(1.0f + __expf(-x));
}
__device__ __forceinline__ float ftnh(float x) {
  float e = __expf(2.0f * x);
  return 1.0f - 2.0f * __builtin_amdgcn_rcpf(e + 1.0f);
}
__device__ __forceinline__ f32x4 MF(bf16x8 a, bf16x8 b, f32x4 c) {
  return __builtin_amdgcn_mfma_f32_16x16x32_bf16(a, b, c, 0, 0, 0);
}

// Repack layout (ushort units) in `wall`:
//  [0,131072)        whhrep [dir2][w8][lane64][frag16][8]
//  [131072,262144)   wihrep [dir2][wq4][j8][kk4][lane64][8]
//  [262144,294912)   linrep [w8][kk8][lane64][8]
//  [294912,425984)   emb_bf [1024][128]
__global__ __launch_bounds__(256) void repack_all2(
    const float* __restrict__ wihf, const float* __restrict__ whhf,
    const float* __restrict__ wihb, const float* __restrict__ whhb,
    const float* __restrict__ emb, const float* __restrict__ linw,
    ushort* __restrict__ wall) {
  int i = blockIdx.x * 256 + threadIdx.x;
  if (i < 131072) {
    int e = i & 7, f = (i >> 3) & 15, lane = (i >> 7) & 63, w = (i >> 13) & 7,
        d = (i >> 16) & 1;
    int nt = f >> 2, kk = f & 3;
    int pcol = w * 64 + nt * 16 + (lane & 15);
    int g = (pcol >> 4) & 3, h = (pcol >> 6) * 16 + (pcol & 15);
    int k = kk * 32 + (lane >> 4) * 8 + e;
    const float* src = d ? whhb : whhf;
    wall[i] = f2bf(src[(g * 128 + h) * 128 + k]);
  } else if (i < 262144) {
    int r = i - 131072;
    int e = r & 7, lane = (r >> 3) & 63, kk = (r >> 9) & 3, j = (r >> 11) & 7,
        wq = (r >> 14) & 3, d = (r >> 16) & 1;
    int pcol = wq * 128 + j * 16 + (lane & 15);
    int g = (pcol >> 4) & 3, h = (pcol >> 6) * 16 + (pcol & 15);
    int k = kk * 32 + (lane >> 4) * 8 + e;
    const float* src = d ? wihb : wihf;
    wall[i] = f2bf(src[(g * 128 + h) * 128 + k]);
  } else if (i < 294912) {
    int r = i - 262144;
    int e = r & 7, lane = (r >> 3) & 63, kk = (r >> 9) & 7, w = (r >> 12) & 7;
    int col = w * 16 + (lane & 15);
    int k = kk * 32 + (lane >> 4) * 8 + e;
    wall[i] = f2bf(linw[col * 256 + k]);
  } else if (i < 425984) {
    int r = i - 294912;
    wall[i] = f2bf(emb[r]);
  }
}

// Fused vocab pipeline (proven rounds 9-14): x-gates (-> gxv), leaf scan
// (T=2), leaf head+gates (-> gcv). One block per 16 vocab entries.
__global__ __launch_bounds__(512) void vocab_all(
    const ushort* __restrict__ emb_bf, const ushort* __restrict__ wihrep,
    const ushort* __restrict__ whhrep, const ushort* __restrict__ linrep,
    const float* __restrict__ linb, const float* __restrict__ bihf,
    const float* __restrict__ bhhf, const float* __restrict__ bihb,
    const float* __restrict__ bhhb, ushort* __restrict__ gxv,
    ushort* __restrict__ gcv) {
  __shared__ __align__(16) ushort sT[2048];
  __shared__ __align__(16) ushort sGx[16384];
  __shared__ __align__(16) ushort sHf[2][2048];
  __shared__ __align__(16) ushort sH[2048];
  const int tid = threadIdx.x;
  const int w = tid >> 6, l = tid & 63, hlo = l & 15, lg = l >> 4;
  const int r0 = lg * 4, k0 = lg * 8;
  const int hcol = w * 16 + hlo;
  const int v0 = blockIdx.x * 16;

  {
    int row = tid >> 5, col0 = (tid & 31) * 4;
    *(ushort4*)(sT + row * 128 + (col0 ^ ((row & 7) << 3))) =
        *(const ushort4*)(emb_bf + (size_t)(v0 + row) * 128 + col0);
  }
  __syncthreads();
  const int dd = w >> 2, wq = w & 3;
  {
    const ushort* wp = wihrep + (size_t)(dd * 4 + wq) * 16384 + l * 8;
    bf16x8 wfv[32];
#pragma unroll
    for (int j = 0; j < 8; ++j)
#pragma unroll
      for (int kk = 0; kk < 4; ++kk)
        wfv[j * 4 + kk] = *(const bf16x8*)(wp + j * 2048 + kk * 512);
    bf16x8 a[4];
#pragma unroll
    for (int kk = 0; kk < 4; ++kk)
      a[kk] = *(const bf16x8*)(sT + hlo * 128 + ((kk * 32 + k0) ^ ((hlo & 7) << 3)));
    f32x4 acc[8];
#pragma unroll
    for (int j = 0; j < 8; ++j) { f32x4 z = {0.f, 0.f, 0.f, 0.f}; acc[j] = z; }
#pragma unroll
    for (int kk = 0; kk < 4; ++kk)
#pragma unroll
      for (int j = 0; j < 8; ++j) acc[j] = MF(a[kk], wfv[j * 4 + kk], acc[j]);
#pragma unroll
    for (int p = 0; p < 2; ++p)
#pragma unroll
      for (int rg = 0; rg < 4; ++rg) {
        int hid = (wq * 2 + p) * 16 + hlo;
        ushort4 q = {f2bf(acc[p * 4 + 0][rg]), f2bf(acc[p * 4 + 1][rg]),
                     f2bf(acc[p * 4 + 2][rg]), f2bf(acc[p * 4 + 3][rg])};
        *(ushort4*)(gxv + (size_t)(v0 + r0 + rg) * 1024 + dd * 512 + hid * 4) = q;
        *(ushort4*)(sGx + (r0 + rg) * 1024 + dd * 512 + hid * 4) = q;
      }
  }
  __syncthreads();

  for (int d = 0; d < 2; ++d) {
    bf16x8 whh[16];
    {
      const ushort* p = whhrep + d * 65536 + w * 8192 + l * 128;
#pragma unroll
      for (int f = 0; f < 16; ++f) whh[f] = *(const bf16x8*)(p + f * 8);
    }
    const float* bih = d ? bihb : bihf;
    const float* bhh = d ? bhhb : bhhf;
    float bs[4];
#pragma unroll
    for (int nt = 0; nt < 4; ++nt)
      bs[nt] = bih[nt * 128 + hcol] + bhh[nt * 128 + hcol];
    ushort4 xg[4];
#pragma unroll
    for (int rg = 0; rg < 4; ++rg)
      xg[rg] = *(const ushort4*)(sGx + (r0 + rg) * 1024 + d * 512 + hcol * 4);
    float c_st[4], hn[4];
#pragma unroll
    for (int rg = 0; rg < 4; ++rg) {
      float g0 = bf2f(xg[rg].x) + bs[0];
      float g2 = bf2f(xg[rg].z) + bs[2];
      float g3 = bf2f(xg[rg].w) + bs[3];
      float c = fsig(g0) * ftnh(g2);
      c_st[rg] = c;
      hn[rg] = fsig(g3) * ftnh(c);
    }
#pragma unroll
    for (int rg = 0; rg < 4; ++rg) {
      int rr = r0 + rg;
      sH[rr * 128 + (hcol ^ ((rr & 7) << 3))] = f2bf(hn[rg]);
    }
    __syncthreads();
    f32x4 a4[4];
#pragma unroll
    for (int rg = 0; rg < 4; ++rg)
#pragma unroll
      for (int nt = 0; nt < 4; ++nt)
        a4[nt][rg] = bf2f(((const ushort*)&xg[rg])[nt]) + bs[nt];
    bf16x8 ah[4];
#pragma unroll
    for (int kk = 0; kk < 4; ++kk)
      ah[kk] = *(const bf16x8*)(sH + hlo * 128 + ((kk * 32 + k0) ^ ((hlo & 7) << 3)));
#pragma unroll
    for (int kk = 0; kk < 4; ++kk)
#pragma unroll
      for (int nt = 0; nt < 4; ++nt) a4[nt] = MF(ah[kk], whh[nt * 4 + kk], a4[nt]);
#pragma unroll
    for (int rg = 0; rg < 4; ++rg) {
      float iv = fsig(a4[0][rg]);
      float fv = fsig(a4[1][rg]);
      float gv = ftnh(a4[2][rg]);
      float ov = fsig(a4[3][rg]);
      float c = fv * c_st[rg] + iv * gv;
      int rr = r0 + rg;
      sHf[d][rr * 128 + (hcol ^ ((rr & 7) << 3))] = f2bf(ov * ftnh(c));
    }
    __syncthreads();
  }

  {
    const float lb = linb[hcol];
    f32x4 hac = {lb, lb, lb, lb};
#pragma unroll
    for (int kk = 0; kk < 8; ++kk) {
      bf16x8 lfr = *(const bf16x8*)(linrep + w * 4096 + kk * 512 + l * 8);
      bf16x8 af = *(const bf16x8*)(&sHf[kk >> 2][0] + hlo * 128 +
                                   (((kk & 3) * 32 + k0) ^ ((hlo & 7) << 3)));
      hac = MF(af, lfr, hac);
    }
#pragma unroll
    for (int rg = 0; rg < 4; ++rg) {
      int rr = r0 + rg;
      sT[rr * 128 + (hcol ^ ((rr & 7) << 3))] = f2bf(ftnh(hac[rg]));
    }
    __syncthreads();
    const ushort* wp = wihrep + (size_t)(dd * 4 + wq) * 16384 + l * 8;
    bf16x8 a[4];
#pragma unroll
    for (int kk = 0; kk < 4; ++kk)
      a[kk] = *(const bf16x8*)(sT + hlo * 128 + ((kk * 32 + k0) ^ ((hlo & 7) << 3)));
    f32x4 acc[8];
#pragma unroll
    for (int j = 0; j < 8; ++j) { f32x4 z = {0.f, 0.f, 0.f, 0.f}; acc[j] = z; }
#pragma unroll
    for (int kk = 0; kk < 4; ++kk)
#pragma unroll
      for (int j = 0; j < 8; ++j) {
        bf16x8 wf = *(const bf16x8*)(wp + j * 2048 + kk * 512);
        acc[j] = MF(a[kk], wf, acc[j]);
      }
#pragma unroll
    for (int p = 0; p < 2; ++p)
#pragma unroll
      for (int rg = 0; rg < 4; ++rg) {
        int hid = (wq * 2 + p) * 16 + hlo;
        ushort4 q = {f2bf(acc[p * 4 + 0][rg]), f2bf(acc[p * 4 + 1][rg]),
                     f2bf(acc[p * 4 + 2][rg]), f2bf(acc[p * 4 + 3][rg])};
        *(ushort4*)(gcv + (size_t)(v0 + r0 + rg) * 1024 + dd * 512 + hid * 4) = q;
      }
  }
}

// L7 scan: MT=4, 64 nodes/block, grid 256 = 1/CU, one pass (R13's proven
// 80us config). Pre-scaled label rows; batched epilogue (one barrier pair).
__global__ __launch_bounds__(512, 1) void scan7(
    const int* __restrict__ xlab, const int* __restrict__ clab,
    const ushort* __restrict__ gxv, const ushort* __restrict__ gsrc,
    const ushort* __restrict__ wihrep, const ushort* __restrict__ whhrep,
    const ushort* __restrict__ linrep, const float* __restrict__ linb,
    const float* __restrict__ bihf, const float* __restrict__ bhhf,
    const float* __restrict__ bihb, const float* __restrict__ bhhb,
    ushort* __restrict__ gdst) {
  __shared__ __align__(16) ushort sH[2][8192];
  __shared__ __align__(16) ushort sHF[2][8192];
  __shared__ __align__(16) ushort sT4[4][2048];
  __shared__ int sLabX[64];   // pre-scaled *1024
  __shared__ int sLabC[256];  // pre-scaled *1024

  const int tid = threadIdx.x;
  const int w = tid >> 6, l = tid & 63, hlo = l & 15, lg = l >> 4;
  const int r0 = lg * 4, k0 = lg * 8;
  const int hcol = w * 16 + hlo;
  const int axswz = (hlo & 7) << 3;
  const int n0 = blockIdx.x * 64;
  const int gofs = hcol * 4;  // column offset within a gate row (d added later)

  for (int i = tid; i < 64; i += 512) sLabX[i] = xlab[n0 + i] << 10;
  for (int i = tid; i < 256; i += 512) sLabC[i] = clab[4 * n0 + i] << 10;
  __syncthreads();

  for (int d = 0; d < 2; ++d) {
    bf16x8 whh[16];
    {
      const ushort* p = whhrep + d * 65536 + w * 8192 + l * 128;
#pragma unroll
      for (int f = 0; f < 16; ++f) whh[f] = *(const bf16x8*)(p + f * 8);
    }
    const float* bih = d ? bihb : bihf;
    const float* bhh = d ? bhhb : bhhf;
    float bs[4];
#pragma unroll
    for (int nt = 0; nt < 4; ++nt)
      bs[nt] = bih[nt * 128 + hcol] + bhh[nt * 128 + hcol];
    const int dof = d * 512 + gofs;

    float c_st[4][4];
    // t = 0 : x-gates only (h0 = 0)
#pragma unroll
    for (int mt = 0; mt < 4; ++mt) {
      ushort4 xg[4];
#pragma unroll
      for (int rg = 0; rg < 4; ++rg)
        xg[rg] = *(const ushort4*)(gxv + (size_t)(sLabX[mt * 16 + r0 + rg] + dof));
#pragma unroll
      for (int rg = 0; rg < 4; ++rg) {
        float g0 = bf2f(xg[rg].x) + bs[0];
        float g2 = bf2f(xg[rg].z) + bs[2];
        float g3 = bf2f(xg[rg].w) + bs[3];
        float c = fsig(g0) * ftnh(g2);
        c_st[mt][rg] = c;
        float h = fsig(g3) * ftnh(c);
        int rr = r0 + rg;
        sH[0][mt * 2048 + rr * 128 + (hcol ^ ((rr & 7) << 3))] = f2bf(h);
      }
    }
    __syncthreads();

#pragma unroll
    for (int t = 1; t < 6; ++t) {
      // issue this step's gate loads upfront (consumed post-MFMA)
      ushort4 gv[4][4];
      if (t < 5) {
        const int ci = d ? (4 - t) : (t - 1);
#pragma unroll
        for (int mt = 0; mt < 4; ++mt)
#pragma unroll
          for (int rg = 0; rg < 4; ++rg)
            gv[mt][rg] = *(const ushort4*)(gsrc +
                (size_t)(sLabC[(mt * 16 + r0 + rg) * 4 + ci] + dof));
      } else {
#pragma unroll
        for (int mt = 0; mt < 4; ++mt)
#pragma unroll
          for (int rg = 0; rg < 4; ++rg)
            gv[mt][rg] = *(const ushort4*)(gxv +
                (size_t)(sLabX[mt * 16 + r0 + rg] + dof));
      }
#pragma unroll
      for (int mt = 0; mt < 4; ++mt) {
        f32x4 a4[4];
#pragma unroll
        for (int nt = 0; nt < 4; ++nt) {
          f32x4 z = {bs[nt], bs[nt], bs[nt], bs[nt]};
          a4[nt] = z;
        }
        bf16x8 ah[4];
#pragma unroll
        for (int kk = 0; kk < 4; ++kk)
          ah[kk] = *(const bf16x8*)(&sH[(t + 1) & 1][mt * 2048] + hlo * 128 +
                                    ((kk * 32 + k0) ^ axswz));
#pragma unroll
        for (int kk = 0; kk < 4; ++kk)
#pragma unroll
          for (int nt = 0; nt < 4; ++nt)
            a4[nt] = MF(ah[kk], whh[nt * 4 + kk], a4[nt]);
#pragma unroll
        for (int rg = 0; rg < 4; ++rg) {
          a4[0][rg] += bf2f(gv[mt][rg].x);
          a4[1][rg] += bf2f(gv[mt][rg].y);
          a4[2][rg] += bf2f(gv[mt][rg].z);
          a4[3][rg] += bf2f(gv[mt][rg].w);
        }
        float hn[4];
#pragma unroll
        for (int rg = 0; rg < 4; ++rg) {
          float iv = fsig(a4[0][rg]);
          float fv = fsig(a4[1][rg]);
          float gg = ftnh(a4[2][rg]);
          float ov = fsig(a4[3][rg]);
          float c = fv * c_st[mt][rg] + iv * gg;
          c_st[mt][rg] = c;
          hn[rg] = ov * ftnh(c);
        }
        ushort* dstp = (t < 5) ? &sH[t & 1][mt * 2048] : &sHF[d][mt * 2048];
#pragma unroll
        for (int rg = 0; rg < 4; ++rg) {
          int rr = r0 + rg;
          dstp[rr * 128 + (hcol ^ ((rr & 7) << 3))] = f2bf(hn[rg]);
        }
      }
      __syncthreads();
    }
  }

  // ---- batched epilogue: all 4 heads -> sT4, one barrier, then gates ----
  const int dd = w >> 2, wq = w & 3;
  const float lb = linb[hcol];
  {
    bf16x8 lf[8];
#pragma unroll
    for (int kk = 0; kk < 8; ++kk)
      lf[kk] = *(const bf16x8*)(linrep + w * 4096 + kk * 512 + l * 8);
#pragma unroll
    for (int mt = 0; mt < 4; ++mt) {
      f32x4 hac = {lb, lb, lb, lb};
#pragma unroll
      for (int kk = 0; kk < 8; ++kk) {
        bf16x8 af = *(const bf16x8*)(&sHF[kk >> 2][mt * 2048] + hlo * 128 +
                                     (((kk & 3) * 32 + k0) ^ axswz));
        hac = MF(af, lf[kk], hac);
      }
#pragma unroll
      for (int rg = 0; rg < 4; ++rg) {
        int rr = r0 + rg;
        sT4[mt][rr * 128 + (hcol ^ ((rr & 7) << 3))] = f2bf(ftnh(hac[rg]));
      }
    }
  }
  __syncthreads();
#pragma unroll
  for (int mt = 0; mt < 4; ++mt) {
    bf16x8 a[4];
#pragma unroll
    for (int kk = 0; kk < 4; ++kk)
      a[kk] = *(const bf16x8*)(&sT4[mt][0] + hlo * 128 + ((kk * 32 + k0) ^ axswz));
#pragma unroll
    for (int half = 0; half < 2; ++half) {
      const ushort* wp = wihrep + (size_t)(dd * 4 + wq) * 16384 +
                         (size_t)(half * 4) * 2048 + l * 8;
      f32x4 acc[4];
#pragma unroll
      for (int j = 0; j < 4; ++j) { f32x4 z = {0.f, 0.f, 0.f, 0.f}; acc[j] = z; }
#pragma unroll
      for (int kk = 0; kk < 4; ++kk)
#pragma unroll
        for (int j = 0; j < 4; ++j) {
          bf16x8 wf = *(const bf16x8*)(wp + j * 2048 + kk * 512);
          acc[j] = MF(a[kk], wf, acc[j]);
        }
      const int hid = (wq * 2 + half) * 16 + hlo;
#pragma unroll
      for (int rg = 0; rg < 4; ++rg) {
        int n = n0 + mt * 16 + r0 + rg;
        ushort4 q = {f2bf(acc[0][rg]), f2bf(acc[1][rg]), f2bf(acc[2][rg]),
                     f2bf(acc[3][rg])};
        *(ushort4*)(gdst + (size_t)n * 1024 + dd * 512 + hid * 4) = q;
      }
    }
  }
}

// Small-level scan (MT=1) with one-step-ahead gate prefetch (R14 proven).
// Pre-scaled rows. Ends with head + own-gates -> gdst.
template <bool CLAB>
__global__ __launch_bounds__(512, 2) void scan_small(
    const int* __restrict__ xlab, const int* __restrict__ clab,
    const ushort* __restrict__ gxv, const ushort* __restrict__ gsrc,
    const ushort* __restrict__ wihrep, const ushort* __restrict__ whhrep,
    const ushort* __restrict__ linrep, const float* __restrict__ linb,
    const float* __restrict__ bihf, const float* __restrict__ bhhf,
    const float* __restrict__ bihb, const float* __restrict__ bhhb,
    ushort* __restrict__ gdst) {
  __shared__ __align__(16) ushort sH[2][2048];
  __shared__ __align__(16) ushort sHF[2][2048];
  __shared__ __align__(16) ushort sT[2048];

  const int tid = threadIdx.x;
  const int w = tid >> 6, l = tid & 63, hlo = l & 15, lg = l >> 4;
  const int r0 = lg * 4, k0 = lg * 8;
  const int hcol = w * 16 + hlo;
  const int axswz = (hlo & 7) << 3;
  const int n0 = blockIdx.x * 16;
  const int gofs = hcol * 4;

  int xrow[4], crow[4];
#pragma unroll
  for (int rg = 0; rg < 4; ++rg) {
    int n = n0 + r0 + rg;
    xrow[rg] = xlab[n] << 10;
    crow[rg] = CLAB ? 0 : ((4 * n) << 10);
  }

  for (int d = 0; d < 2; ++d) {
    bf16x8 whh[16];
    {
      const ushort* p = whhrep + d * 65536 + w * 8192 + l * 128;
#pragma unroll
      for (int f = 0; f < 16; ++f) whh[f] = *(const bf16x8*)(p + f * 8);
    }
    const float* bih = d ? bihb : bihf;
    const float* bhh = d ? bhhb : bhhf;
    float bs[4];
#pragma unroll
    for (int nt = 0; nt < 4; ++nt)
      bs[nt] = bih[nt * 128 + hcol] + bhh[nt * 128 + hcol];
    const int dof = d * 512 + gofs;

    float c_st[4];
    ushort4 gv[4];
    // t = 0 : x-gates (no MFMA; h0 = 0)
    {
      ushort4 xg[4];
#pragma unroll
      for (int rg = 0; rg < 4; ++rg)
        xg[rg] = *(const ushort4*)(gxv + (size_t)(xrow[rg] + dof));
#pragma unroll
      for (int rg = 0; rg < 4; ++rg) {
        float g0 = bf2f(xg[rg].x) + bs[0];
        float g2 = bf2f(xg[rg].z) + bs[2];
        float g3 = bf2f(xg[rg].w) + bs[3];
        float c = fsig(g0) * ftnh(g2);
        c_st[rg] = c;
        float h = fsig(g3) * ftnh(c);
        int rr = r0 + rg;
        sH[0][rr * 128 + (hcol ^ ((rr & 7) << 3))] = f2bf(h);
      }
    }
    // prefetch gates for t = 1
    {
      const int ci = d ? 3 : 0;
#pragma unroll
      for (int rg = 0; rg < 4; ++rg) {
        int row = CLAB ? (clab[4 * (n0 + r0 + rg) + ci] << 10)
                       : (crow[rg] + (ci << 10));
        gv[rg] = *(const ushort4*)(gsrc + (size_t)(row + dof));
      }
    }
    __syncthreads();

#pragma unroll
    for (int t = 1; t < 6; ++t) {
      ushort4 gvn[4];
      if (t < 4) {
        const int ci = d ? (3 - t) : t;
#pragma unroll
        for (int rg = 0; rg < 4; ++rg) {
          int row = CLAB ? (clab[4 * (n0 + r0 + rg) + ci] << 10)
                         : (crow[rg] + (ci << 10));
          gvn[rg] = *(const ushort4*)(gsrc + (size_t)(row + dof));
        }
      } else if (t == 4) {
#pragma unroll
        for (int rg = 0; rg < 4; ++rg)
          gvn[rg] = *(const ushort4*)(gxv + (size_t)(xrow[rg] + dof));
      }
      f32x4 a4[4];
#pragma unroll
      for (int nt = 0; nt < 4; ++nt) {
        f32x4 z = {bs[nt], bs[nt], bs[nt], bs[nt]};
        a4[nt] = z;
      }
      bf16x8 ah[4];
#pragma unroll
      for (int kk = 0; kk < 4; ++kk)
        ah[kk] = *(const bf16x8*)(&sH[(t + 1) & 1][0] + hlo * 128 +
                                  ((kk * 32 + k0) ^ axswz));
#pragma unroll
      for (int kk = 0; kk < 4; ++kk)
#pragma unroll
        for (int nt = 0; nt < 4; ++nt) a4[nt] = MF(ah[kk], whh[nt * 4 + kk], a4[nt]);
#pragma unroll
      for (int rg = 0; rg < 4; ++rg) {
        a4[0][rg] += bf2f(gv[rg].x);
        a4[1][rg] += bf2f(gv[rg].y);
        a4[2][rg] += bf2f(gv[rg].z);
        a4[3][rg] += bf2f(gv[rg].w);
      }
      float hn[4];
#pragma unroll
      for (int rg = 0; rg < 4; ++rg) {
        float iv = fsig(a4[0][rg]);
        float fv = fsig(a4[1][rg]);
        float gg = ftnh(a4[2][rg]);
        float ov = fsig(a4[3][rg]);
        float c = fv * c_st[rg] + iv * gg;
        c_st[rg] = c;
        hn[rg] = ov * ftnh(c);
      }
      ushort* dstp = (t < 5) ? &sH[t & 1][0] : &sHF[d][0];
#pragma unroll
      for (int rg = 0; rg < 4; ++rg) {
        int rr = r0 + rg;
        dstp[rr * 128 + (hcol ^ ((rr & 7) << 3))] = f2bf(hn[rg]);
      }
      if (t < 5) {
#pragma unroll
        for (int rg = 0; rg < 4; ++rg) gv[rg] = gvn[rg];
      }
      __syncthreads();
    }
  }

  // ---- head + own gates ----
  const int dd = w >> 2, wq = w & 3;
  const float lb = linb[hcol];
  f32x4 hac = {lb, lb, lb, lb};
#pragma unroll
  for (int kk = 0; kk < 8; ++kk) {
    bf16x8 lfr = *(const bf16x8*)(linrep + w * 4096 + kk * 512 + l * 8);
    bf16x8 af = *(const bf16x8*)(&sHF[kk >> 2][0] + hlo * 128 +
                                 (((kk & 3) * 32 + k0) ^ axswz));
    hac = MF(af, lfr, hac);
  }
#pragma unroll
  for (int rg = 0; rg < 4; ++rg) {
    int rr = r0 + rg;
    sT[rr * 128 + (hcol ^ ((rr & 7) << 3))] = f2bf(ftnh(hac[rg]));
  }
  __syncthreads();
  bf16x8 a[4];
#pragma unroll
  for (int kk = 0; kk < 4; ++kk)
    a[kk] = *(const bf16x8*)(sT + hlo * 128 + ((kk * 32 + k0) ^ axswz));
#pragma unroll
  for (int half = 0; half < 2; ++half) {
    const ushort* wp =
        wihrep + (size_t)(dd * 4 + wq) * 16384 + (size_t)(half * 4) * 2048 + l * 8;
    f32x4 acc[4];
#pragma unroll
    for (int j = 0; j < 4; ++j) { f32x4 z = {0.f, 0.f, 0.f, 0.f}; acc[j] = z; }
#pragma unroll
    for (int kk = 0; kk < 4; ++kk)
#pragma unroll
      for (int j = 0; j < 4; ++j) {
        bf16x8 wf = *(const bf16x8*)(wp + j * 2048 + kk * 512);
        acc[j] = MF(a[kk], wf, acc[j]);
      }
    const int hid = (wq * 2 + half) * 16 + hlo;
#pragma unroll
    for (int rg = 0; rg < 4; ++rg) {
      int n = n0 + r0 + rg;
      ushort4 q = {f2bf(acc[0][rg]), f2bf(acc[1][rg]), f2bf(acc[2][rg]),
                   f2bf(acc[3][rg])};
      *(ushort4*)(gdst + (size_t)n * 1024 + dd * 512 + hid * 4) = q;
    }
  }
}

// Levels 2,1,0 + final head in ONE block; gates routed through LDS.
__global__ __launch_bounds__(512) void tail_lvls(
    const int* __restrict__ labels, const ushort* __restrict__ gxv,
    const ushort* __restrict__ gc3, const ushort* __restrict__ wihrep,
    const ushort* __restrict__ whhrep, const ushort* __restrict__ linrep,
    const float* __restrict__ linb, const float* __restrict__ bihf,
    const float* __restrict__ bhhf, const float* __restrict__ bihb,
    const float* __restrict__ bhhb, float* __restrict__ outp) {
  __shared__ __align__(16) ushort sH[2][2048];
  __shared__ __align__(16) ushort sHF[2][2048];
  __shared__ __align__(16) ushort sT[2048];
  __shared__ __align__(16) ushort sGc[16384];

  const int tid = threadIdx.x;
  const int w = tid >> 6, l = tid & 63, hlo = l & 15, lg = l >> 4;
  const int r0 = lg * 4, k0 = lg * 8;
  const int hcol = w * 16 + hlo;
  const int axswz = (hlo & 7) << 3;
  const int dd = w >> 2, wq = w & 3;

  bf16x8 lf[8];
#pragma unroll
  for (int kk = 0; kk < 8; ++kk)
    lf[kk] = *(const bf16x8*)(linrep + w * 4096 + kk * 512 + l * 8);
  const float lb = linb[hcol];
  const int cnts[3] = {16, 4, 1};
  const int xoffs[3] = {5, 1, 0};

  for (int p = 0; p < 3; ++p) {
    const int cnt = cnts[p];
    const int* xlab = labels + xoffs[p];
    const ushort* gsrc = (p == 0) ? gc3 : (const ushort*)sGc;
    int nnr[4];
#pragma unroll
    for (int rg = 0; rg < 4; ++rg) {
      int n = r0 + rg;
      nnr[rg] = (n < cnt) ? n : (cnt - 1);
    }

    for (int d = 0; d < 2; ++d) {
      bf16x8 whh[16];
      {
        const ushort* pw = whhrep + d * 65536 + w * 8192 + l * 128;
#pragma unroll
        for (int f = 0; f < 16; ++f) whh[f] = *(const bf16x8*)(pw + f * 8);
      }
      const float* bih = d ? bihb : bihf;
      const float* bhh = d ? bhhb : bhhf;
      float bs[4];
#pragma unroll
      for (int nt = 0; nt < 4; ++nt)
        bs[nt] = bih[nt * 128 + hcol] + bhh[nt * 128 + hcol];

      ushort4 xg[4];
#pragma unroll
      for (int rg = 0; rg < 4; ++rg)
        xg[rg] = *(const ushort4*)(gxv + (size_t)xlab[nnr[rg]] * 1024 +
                                   d * 512 + hcol * 4);
      float c_st[4];
#pragma unroll
      for (int t = 0; t < 6; ++t) {
        const bool isx = (t == 0) || (t == 5);
        f32x4 a4[4];
#pragma unroll
        for (int rg = 0; rg < 4; ++rg) {
          ushort4 u;
          if (isx) {
            u = xg[rg];
          } else {
            const int ci = d ? (4 - t) : (t - 1);
            int row = 4 * nnr[rg] + ci;
            u = *(const ushort4*)(gsrc + (size_t)row * 1024 + d * 512 + hcol * 4);
          }
#pragma unroll
          for (int nt = 0; nt < 4; ++nt)
            a4[nt][rg] = bf2f(((const ushort*)&u)[nt]) + bs[nt];
        }
        if (t > 0) {
          bf16x8 ah[4];
#pragma unroll
          for (int kk = 0; kk < 4; ++kk)
            ah[kk] = *(const bf16x8*)(&sH[(t + 1) & 1][0] + hlo * 128 +
                                      ((kk * 32 + k0) ^ axswz));
#pragma unroll
          for (int kk = 0; kk < 4; ++kk)
#pragma unroll
            for (int nt = 0; nt < 4; ++nt)
              a4[nt] = MF(ah[kk], whh[nt * 4 + kk], a4[nt]);
        }
        float hn[4];
#pragma unroll
        for (int rg = 0; rg < 4; ++rg) {
          float iv = fsig(a4[0][rg]);
          float fv = fsig(a4[1][rg]);
          float gv = ftnh(a4[2][rg]);
          float ov = fsig(a4[3][rg]);
          float c = (t == 0) ? (iv * gv) : (fv * c_st[rg] + iv * gv);
          c_st[rg] = c;
          hn[rg] = ov * ftnh(c);
        }
        ushort* dstp = (t < 5) ? &sH[t & 1][0] : &sHF[d][0];
#pragma unroll
        for (int rg = 0; rg < 4; ++rg) {
          int rr = r0 + rg;
          dstp[rr * 128 + (hcol ^ ((rr & 7) << 3))] = f2bf(hn[rg]);
        }
        __syncthreads();
      }
    }

    f32x4 hac = {lb, lb, lb, lb};
#pragma unroll
    for (int kk = 0; kk < 8; ++kk) {
      bf16x8 af = *(const bf16x8*)(&sHF[kk >> 2][0] + hlo * 128 +
                                   (((kk & 3) * 32 + k0) ^ axswz));
      hac = MF(af, lf[kk], hac);
    }
    if (p == 2) {
      if (lg == 0) outp[hcol] = ftnh(hac[0]);
      return;
    }
    __syncthreads();
#pragma unroll
    for (int rg = 0; rg < 4; ++rg) {
      int rr = r0 + rg;
      sT[rr * 128 + (hcol ^ ((rr & 7) << 3))] = f2bf(ftnh(hac[rg]));
    }
    __syncthreads();
    bf16x8 a[4];
#pragma unroll
    for (int kk = 0; kk < 4; ++kk)
      a[kk] = *(const bf16x8*)(sT + hlo * 128 + ((kk * 32 + k0) ^ axswz));
    f32x4 acc[8];
#pragma unroll
    for (int j = 0; j < 8; ++j) { f32x4 z = {0.f, 0.f, 0.f, 0.f}; acc[j] = z; }
    const ushort* wp = wihrep + (size_t)(dd * 4 + wq) * 16384 + l * 8;
#pragma unroll
    for (int kk = 0; kk < 4; ++kk)
#pragma unroll
      for (int j = 0; j < 8; ++j) {
        bf16x8 wf = *(const bf16x8*)(wp + j * 2048 + kk * 512);
        acc[j] = MF(a[kk], wf, acc[j]);
      }
#pragma unroll
    for (int pp = 0; pp < 2; ++pp)
#pragma unroll
      for (int rg = 0; rg < 4; ++rg) {
        int n = r0 + rg;
        if (n < cnt) {
          int hid = (wq * 2 + pp) * 16 + hlo;
          ushort4 q = {f2bf(acc[pp * 4 + 0][rg]), f2bf(acc[pp * 4 + 1][rg]),
                       f2bf(acc[pp * 4 + 2][rg]), f2bf(acc[pp * 4 + 3][rg])};
          *(ushort4*)(sGc + (size_t)n * 1024 + dd * 512 + hid * 4) = q;
        }
      }
    __syncthreads();
  }
}

extern "C" void kernel_launch(void* const* d_in, const int* in_sizes, int n_in,
                              void* d_out, int out_size, void* d_ws, size_t ws_size,
                              hipStream_t stream) {
  const int* labels = (const int*)d_in[0];
  const float* emb = (const float*)d_in[1];
  const float* w_ih_f = (const float*)d_in[2];
  const float* w_hh_f = (const float*)d_in[3];
  const float* b_ih_f = (const float*)d_in[4];
  const float* b_hh_f = (const float*)d_in[5];
  const float* w_ih_b = (const float*)d_in[6];
  const float* w_hh_b = (const float*)d_in[7];
  const float* b_ih_b = (const float*)d_in[8];
  const float* b_hh_b = (const float*)d_in[9];
  const float* lin_w = (const float*)d_in[10];
  const float* lin_b = (const float*)d_in[11];
  float* out = (float*)d_out;

  ushort* gxv = (ushort*)d_ws;         // 1,048,576
  ushort* gcA = gxv + 1048576;         // 16,777,216 (L7 / L5 / L3 gates)
  ushort* gcB = gcA + 16777216;        // 4,194,304  (gcv / L6 / L4 gates)
  ushort* gcv = gcB;
  ushort* wall = gcB + 4194304;        // 425,984
  ushort* whhrep = wall;
  ushort* wihrep = wall + 131072;
  ushort* linrep = wall + 262144;
  ushort* emb_bf = wall + 294912;

  repack_all2<<<1664, 256, 0, stream>>>(w_ih_f, w_hh_f, w_ih_b, w_hh_b, emb,
                                        lin_w, wall);
  vocab_all<<<64, 512, 0, stream>>>(emb_bf, wihrep, whhrep, linrep, lin_b,
                                    b_ih_f, b_hh_f, b_ih_b, b_hh_b, gxv, gcv);
  // L7: 16384 nodes, 64/block -> 256 blocks (1/CU, one pass)
  scan7<<<256, 512, 0, stream>>>(labels + 5461, labels + 21845, gxv, gcv,
                                 wihrep, whhrep, linrep, lin_b, b_ih_f, b_hh_f,
                                 b_ih_b, b_hh_b, gcA);
  // L6: 4096 nodes -> 256 blocks
  scan_small<false><<<256, 512, 0, stream>>>(
      labels + 1365, nullptr, gxv, gcA, wihrep, whhrep, linrep, lin_b, b_ih_f,
      b_hh_f, b_ih_b, b_hh_b, gcB);
  // L5: 1024 -> 64 blocks
  scan_small<false><<<64, 512, 0, stream>>>(
      labels + 341, nullptr, gxv, gcB, wihrep, whhrep, linrep, lin_b, b_ih_f,
      b_hh_f, b_ih_b, b_hh_b, gcA);
  // L4: 256 -> 16 blocks
  scan_small<false><<<16, 512, 0, stream>>>(
      labels + 85, nullptr, gxv, gcA, wihrep, whhrep, linrep, lin_b, b_ih_f,
      b_hh_f, b_ih_b, b_hh_b, gcB);
  // L3: 64 -> 4 blocks
  scan_small<false><<<4, 512, 0, stream>>>(
      labels + 21, nullptr, gxv, gcB, wihrep, whhrep, linrep, lin_b, b_ih_f,
      b_hh_f, b_ih_b, b_hh_b, gcA);
  // L2+L1+L0+head, one block
  tail_lvls<<<1, 512, 0, stream>>>(labels, gxv, gcA, wihrep, whhrep, linrep,
                                   lin_b, b_ih_f, b_hh_f, b_ih_b, b_hh_b, out);
}